// Round 6
// baseline (117.945 us; speedup 1.0000x reference)
//
#include <hip/hip_runtime.h>
#include <stdint.h>

#define HH 512
#define WW 512
#define HW (HH * WW)          // 262144 pixels per image
#define WPR 8                 // u64 words per row (global layout)
#define NWORDS (HH * WPR)     // 4096 words per image
#define NTHREADS 1024
#define NB 16                 // batch
#define NIMG (2 * NB)         // 32 masks

// padded LDS layout for final skel: rows -1..512, cols -1..8 (stride 10)
#define LSTR 10
#define LROWS (HH + 2)        // 514
#define LWORDS (LROWS * LSTR) // 5140 words

typedef unsigned long long u64;

// Zhang-Suen sub-step core on prebuilt neighbor views (bit k = pixel col k).
__device__ __forceinline__ u64 zs_core(u64 cc, u64 P2, u64 P3, u64 P4, u64 P5,
                                       u64 P6, u64 P7, u64 P8, u64 P9, int step) {
    u64 ab = P2 ^ P3;
    u64 s1 = ab ^ P4, c1 = (P2 & P3) | (ab & P4);
    u64 de = P5 ^ P6;
    u64 s2 = de ^ P7, c2 = (P5 & P6) | (de & P7);
    u64 s3 = P8 ^ P9, c3 = P8 & P9;
    u64 gh = s1 ^ s2;
    u64 b0 = gh ^ s3, c4 = (s1 & s2) | (gh & s3);
    u64 ij = c1 ^ c2;
    u64 s4 = ij ^ c3, c5 = (c1 & c2) | (ij & c3);
    u64 b1 = s4 ^ c4, c6 = s4 & c4;
    u64 b2 = c5 ^ c6, b3 = c5 & c6;

    u64 Bge2 = b1 | b2 | b3;
    u64 Ble6 = ~(b3 | (b2 & b1 & b0));

    u64 a1, a2, t;
    t = ~P2 & P3; a1 = t; a2 = 0ULL;
    t = ~P3 & P4; a2 |= a1 & t; a1 |= t;
    t = ~P4 & P5; a2 |= a1 & t; a1 |= t;
    t = ~P5 & P6; a2 |= a1 & t; a1 |= t;
    t = ~P6 & P7; a2 |= a1 & t; a1 |= t;
    t = ~P7 & P8; a2 |= a1 & t; a1 |= t;
    t = ~P8 & P9; a2 |= a1 & t; a1 |= t;
    t = ~P9 & P2; a2 |= a1 & t; a1 |= t;
    u64 Aeq1 = a1 & ~a2;

    u64 sccond = (step == 0) ? ~((P4 & P6) & (P2 | P8))
                             : ~((P2 & P8) & (P4 | P6));

    return cc & ~(Bge2 & Ble6 & Aeq1 & sccond);
}

// ---------------- pack: full-GPU binarize (2048 blocks x 256 threads) --------
__global__ __launch_bounds__(256)
void pack_kernel(const float* __restrict__ y_pred,
                 const float* __restrict__ y_true,
                 u64* __restrict__ bits /* buf1 */,
                 int* __restrict__ cnt /* 64 cnt + 32 flags + 1 done */) {
    int tid = threadIdx.x;
    if (blockIdx.x == 0 && tid < 4 * NB + NIMG + 1) cnt[tid] = 0;

    int t = blockIdx.x * 256 + tid;                      // ushort index 0..524287
    size_t g0 = (size_t)t * 16;                          // pixel index, concat space
    const float* src;
    size_t off;
    if (g0 < (size_t)NB * HW) { src = y_pred; off = g0; }
    else                      { src = y_true; off = g0 - (size_t)NB * HW; }
    const float4* s4 = (const float4*)(src + off);       // 64B-aligned
    float4 a = s4[0];
    float4 b = s4[1];
    float4 c = s4[2];
    float4 d = s4[3];
    unsigned m =
        ((unsigned)(a.x > 0.5f) << 0)  | ((unsigned)(a.y > 0.5f) << 1)  |
        ((unsigned)(a.z > 0.5f) << 2)  | ((unsigned)(a.w > 0.5f) << 3)  |
        ((unsigned)(b.x > 0.5f) << 4)  | ((unsigned)(b.y > 0.5f) << 5)  |
        ((unsigned)(b.z > 0.5f) << 6)  | ((unsigned)(b.w > 0.5f) << 7)  |
        ((unsigned)(c.x > 0.5f) << 8)  | ((unsigned)(c.y > 0.5f) << 9)  |
        ((unsigned)(c.z > 0.5f) << 10) | ((unsigned)(c.w > 0.5f) << 11) |
        ((unsigned)(d.x > 0.5f) << 12) | ((unsigned)(d.y > 0.5f) << 13) |
        ((unsigned)(d.z > 0.5f) << 14) | ((unsigned)(d.w > 0.5f) << 15);
    ((unsigned short*)bits)[t] = (unsigned short)m;
}

// ---------------- strip thinning: 256 blocks, full GPU ----------------------
// Each block owns 64 interior rows of one image plus a 24-row halo each side.
// Runs up to 12 ZS iterations (24 phases) with NO inter-block communication:
// validity shrinks 1 row/phase, halo 24 covers 24 phases, interior exact.
// Thinning is monotone -> local fixpoint exists; early-exit when the whole
// local domain has a clean iteration. rec=1: record per-image "not converged"
// flag (any change in the final executed local iteration).
#define SSTRIPS 8
#define SIROWS (HH / SSTRIPS)          // 64 interior rows
#define SHALO 24
#define SDROWS (SIROWS + 2 * SHALO)    // 112 domain rows
#define STHREADS (SDROWS * WPR)        // 896 threads, 1 word each
#define SITERS (SHALO / 2)             // 12 local iterations = 24 phases
#define SSTR 10
#define SLWORDS ((SDROWS + 2) * SSTR)  // 1140 words per buffer

__global__ __launch_bounds__(STHREADS)
void strip_kernel(const u64* __restrict__ src, u64* __restrict__ dst,
                  int* __restrict__ flags, int rec) {
    __shared__ u64 Mb[2][SLWORDS];     // 2 x 9120 B
    __shared__ int s_any[3];

    int bx = blockIdx.x;
    int img = bx >> 3;
    int s = bx & 7;
    int tid = threadIdx.x;             // 0..895
    int lane = tid & 63;
    int r = tid >> 3;                  // domain row 0..111
    int c = tid & 7;
    int gr = s * SIROWS - SHALO + r;   // global row of this thread's word

    // zero both buffers (covers guards; interiors overwritten below / phase 0)
    for (int i = tid; i < SLWORDS; i += STHREADS) { Mb[0][i] = 0; Mb[1][i] = 0; }
    if (tid < 3) s_any[tid] = 0;
    __syncthreads();

    const u64* gsrc = src + (size_t)img * NWORDS;
    u64 v = (gr >= 0 && gr < HH) ? gsrc[gr * WPR + c] : 0ULL;
    int base = (r + 1) * SSTR + (c + 1);
    Mb[0][base] = v;

    bool prevchg = true;
    int it = 0;
    bool done = false;
    for (;;) {
        for (int step = 0; step < 2; ++step) {
            __syncthreads();           // orders prior phase's writes
            if (step == 0 && it > 0) {
                if (s_any[(it + 2) % 3] == 0) { done = true; break; }
            }
            const u64* Ms = Mb[step];
            u64* Md = Mb[step ^ 1];
            u64 cc = Ms[base];
            u64 nv = cc;
            bool chg = false;
            if (cc) {                  // zero words can never gain pixels
                u64 nm = Ms[base - SSTR - 1], nc = Ms[base - SSTR], np = Ms[base - SSTR + 1];
                u64 cm = Ms[base - 1],                              cp = Ms[base + 1];
                u64 sm = Ms[base + SSTR - 1], sc = Ms[base + SSTR], sp = Ms[base + SSTR + 1];
                u64 P2 = nc;
                u64 P3 = (nc >> 1) | (np << 63);
                u64 P4 = (cc >> 1) | (cp << 63);
                u64 P5 = (sc >> 1) | (sp << 63);
                u64 P6 = sc;
                u64 P7 = (sc << 1) | (sm >> 63);
                u64 P8 = (cc << 1) | (cm >> 63);
                u64 P9 = (nc << 1) | (nm >> 63);
                nv = zs_core(cc, P2, P3, P4, P5, P6, P7, P8, P9, step);
                chg = (nv != cc);
            }
            // Md holds state from 2 phases back; skip store iff unchanged both
            if (chg | prevchg) Md[base] = nv;
            prevchg = chg;
            u64 bal = __ballot(chg);
            if (bal && lane == 0) s_any[it % 3] = 1;   // benign same-value race
            if (step == 1 && tid == 0) s_any[(it + 1) % 3] = 0;
        }
        if (done) break;
        if (++it >= SITERS) break;
    }
    __syncthreads();                   // make last iteration's s_any visible
    // lastAny: did the final executed iteration change anything?
    int lastAny = done ? 0 : s_any[(SITERS - 1) % 3];

    // store interior rows (phase count even at both exits -> state in Mb[0])
    if (r >= SHALO && r < SHALO + SIROWS) {
        dst[(size_t)img * NWORDS + gr * WPR + c] = Mb[0][base];
    }
    if (rec && lastAny && tid == 0) flags[img] = 1;    // same-value races benign
}

// ---------------- final skeletonize: fallback, skips converged images --------
__global__ __launch_bounds__(NTHREADS, 4)
void skel_kernel(u64* __restrict__ bits, const int* __restrict__ flags) {
    __shared__ u64 Mb[2][LWORDS];
    __shared__ unsigned int Cpb[2][130];
    __shared__ int s_any[3];

    int bx = blockIdx.x;
    if (flags[bx] == 0) return;        // strips already converged this image

    int tid = threadIdx.x;
    int lane = tid & 63;
    int c = tid & 7;
    int rb = tid >> 3;

    u64* gm = bits + (size_t)bx * NWORDS;

    if (tid < LROWS) {
        int i = tid;
        if (i == 0 || i == LROWS - 1) {
            #pragma unroll
            for (int j = 0; j < LSTR; ++j) { Mb[0][i * LSTR + j] = 0; Mb[1][i * LSTR + j] = 0; }
        } else {
            Mb[0][i * LSTR + 0] = 0; Mb[0][i * LSTR + 9] = 0;
            Mb[1][i * LSTR + 0] = 0; Mb[1][i * LSTR + 9] = 0;
        }
    }
    {
        const ulonglong2* s2 = (const ulonglong2*)gm;
        #pragma unroll
        for (int k = 0; k < 2; ++k) {
            int i = k * NTHREADS + tid;
            ulonglong2 v = s2[i];
            int wi = i * 2;
            int r = wi >> 3, c2 = wi & 7;
            int li = (r + 1) * LSTR + c2 + 1;
            Mb[0][li] = v.x;
            Mb[0][li + 1] = v.y;
        }
    }
    if (tid < 130) {
        Cpb[0][tid] = (tid >= 1 && tid <= 128) ? 0x1FEu : 0u;
        Cpb[1][tid] = 0u;
    }
    if (tid < 3) s_any[tid] = 0;

    unsigned dl = 0x1FEu;
    bool prevchg = true;
    int base = (rb * 4 + 1) * LSTR + (c + 1);

    int it = 0;
    bool done = false;
    for (;;) {
        for (int step = 0; step < 2; ++step) {
            __syncthreads();
            if (step == 0 && it > 0) {
                if (s_any[(it + 2) % 3] == 0) { done = true; break; }
            }
            const u64* Ms = Mb[step];
            u64* Md = Mb[step ^ 1];
            const unsigned* CpS = Cpb[step];
            unsigned* CpD = Cpb[step ^ 1];

            unsigned need = ((CpS[rb] | CpS[rb + 1] | CpS[rb + 2]) >> c) & 7u;
            bool chg = false;
            if (need) {
                u64 Ca, Ea, Wa, Cb, Eb, Wb, Cc, Ec, Wc;
                {   int a = base - LSTR;
                    u64 x = Ms[a], mm = Ms[a - 1], pp = Ms[a + 1];
                    Ca = x; Ea = (x >> 1) | (pp << 63); Wa = (x << 1) | (mm >> 63); }
                {   int a = base;
                    u64 x = Ms[a], mm = Ms[a - 1], pp = Ms[a + 1];
                    Cb = x; Eb = (x >> 1) | (pp << 63); Wb = (x << 1) | (mm >> 63); }
                u64 nv0 = 0, nv1 = 0, nv2 = 0, nv3 = 0;
                {   int a = base + LSTR;
                    u64 x = Ms[a], mm = Ms[a - 1], pp = Ms[a + 1];
                    Cc = x; Ec = (x >> 1) | (pp << 63); Wc = (x << 1) | (mm >> 63);
                    if (Cb) nv0 = zs_core(Cb, Ca, Ea, Eb, Ec, Cc, Wc, Wb, Wa, step);
                    chg |= (nv0 != Cb);
                    Ca = Cb; Ea = Eb; Wa = Wb; Cb = Cc; Eb = Ec; Wb = Wc; }
                {   int a = base + 2 * LSTR;
                    u64 x = Ms[a], mm = Ms[a - 1], pp = Ms[a + 1];
                    Cc = x; Ec = (x >> 1) | (pp << 63); Wc = (x << 1) | (mm >> 63);
                    if (Cb) nv1 = zs_core(Cb, Ca, Ea, Eb, Ec, Cc, Wc, Wb, Wa, step);
                    chg |= (nv1 != Cb);
                    Ca = Cb; Ea = Eb; Wa = Wb; Cb = Cc; Eb = Ec; Wb = Wc; }
                {   int a = base + 3 * LSTR;
                    u64 x = Ms[a], mm = Ms[a - 1], pp = Ms[a + 1];
                    Cc = x; Ec = (x >> 1) | (pp << 63); Wc = (x << 1) | (mm >> 63);
                    if (Cb) nv2 = zs_core(Cb, Ca, Ea, Eb, Ec, Cc, Wc, Wb, Wa, step);
                    chg |= (nv2 != Cb);
                    Ca = Cb; Ea = Eb; Wa = Wb; Cb = Cc; Eb = Ec; Wb = Wc; }
                {   int a = base + 4 * LSTR;
                    u64 x = Ms[a], mm = Ms[a - 1], pp = Ms[a + 1];
                    Cc = x; Ec = (x >> 1) | (pp << 63); Wc = (x << 1) | (mm >> 63);
                    if (Cb) nv3 = zs_core(Cb, Ca, Ea, Eb, Ec, Cc, Wc, Wb, Wa, step);
                    chg |= (nv3 != Cb); }
                if (chg | prevchg) {
                    Md[base] = nv0;
                    Md[base + LSTR] = nv1;
                    Md[base + 2 * LSTR] = nv2;
                    Md[base + 3 * LSTR] = nv3;
                }
            }
            prevchg = chg;
            u64 bal = __ballot(chg);
            if (bal && lane == 0) s_any[it % 3] = 1;
            if ((lane & 7) == 0) {
                unsigned byte = ((unsigned)(bal >> lane) & 0xFFu) << 1;
                CpD[rb + 1] = byte | dl;
                dl = byte;
            }
            if (step == 1 && tid == 0) s_any[(it + 1) % 3] = 0;
        }
        if (done || it >= 1024) break;
        ++it;
    }

    {
        ulonglong2* d2 = (ulonglong2*)gm;
        #pragma unroll
        for (int k = 0; k < 2; ++k) {
            int i = k * NTHREADS + tid;
            int wi = i * 2;
            int r = wi >> 3, c2 = wi & 7;
            int li = (r + 1) * LSTR + c2 + 1;
            ulonglong2 v;
            v.x = Mb[0][li];
            v.y = Mb[0][li + 1];
            d2[i] = v;
        }
    }
}

// ---------------- count (+ fused final reduce): 8 strips/image, 128 blocks ---
#define STRIPS 8
#define SROWS (HH / STRIPS)
#define SR2 (SROWS + 6)

__device__ __forceinline__ u64 ldws(const u64* M, int r, int c) {
    return (c < 0 || c >= WPR) ? 0ULL : M[r * WPR + c];
}

__device__ __forceinline__ u64 dil3s(const u64* M, int r, int c) {
    u64 cm = ldws(M, r, c - 1), cc = ldws(M, r, c), cp = ldws(M, r, c + 1);
    u64 h = cc
          | (cc >> 1) | (cp << 63)
          | (cc >> 2) | (cp << 62)
          | (cc >> 3) | (cp << 61)
          | (cc << 1) | (cm >> 63)
          | (cc << 2) | (cm >> 62)
          | (cc << 3) | (cm >> 61);
    u64 um = ldws(M, r - 1, c - 1) | ldws(M, r + 1, c - 1) | ldws(M, r - 2, c - 1) | ldws(M, r + 2, c - 1);
    u64 uc = ldws(M, r - 1, c    ) | ldws(M, r + 1, c    ) | ldws(M, r - 2, c    ) | ldws(M, r + 2, c    );
    u64 up = ldws(M, r - 1, c + 1) | ldws(M, r + 1, c + 1) | ldws(M, r - 2, c + 1) | ldws(M, r + 2, c + 1);
    h |= uc
       | (uc >> 1) | (up << 63)
       | (uc >> 2) | (up << 62)
       | (uc << 1) | (um >> 63)
       | (uc << 2) | (um >> 62);
    h |= ldws(M, r - 3, c) | ldws(M, r + 3, c);
    return h;
}

__global__ __launch_bounds__(256)
void count_kernel(const u64* __restrict__ skel, int* __restrict__ cnt,
                  int* __restrict__ done, float* __restrict__ out) {
    __shared__ u64 P[SR2 * WPR];
    __shared__ u64 G[SR2 * WPR];
    __shared__ int acc[4];
    __shared__ int s_last;

    int b = blockIdx.x / STRIPS;
    int s = blockIdx.x % STRIPS;
    int tid = threadIdx.x;
    int r0 = s * SROWS - 3;

    const u64* sp = skel + (size_t)b * NWORDS;
    const u64* sg = skel + (size_t)(NB + b) * NWORDS;
    for (int i = tid; i < SR2 * WPR; i += 256) {
        int gr = r0 + (i >> 3);
        bool in = (gr >= 0 && gr < HH);
        int gi = gr * WPR + (i & 7);
        P[i] = in ? sp[gi] : 0ULL;
        G[i] = in ? sg[gi] : 0ULL;
    }
    if (tid < 4) acc[tid] = 0;
    __syncthreads();

    int cp = 0, cg = 0, tp = 0, fnh = 0;
    #pragma unroll
    for (int k = 0; k < 2; ++k) {
        int w = k * 256 + tid;
        int r = (w >> 3) + 3, c = w & 7;
        u64 pw = P[r * WPR + c], gw = G[r * WPR + c];
        cp  += __popcll(pw);
        cg  += __popcll(gw);
        tp  += __popcll(pw & dil3s(G, r, c));
        fnh += __popcll(gw & dil3s(P, r, c));
    }
    #pragma unroll
    for (int o = 32; o > 0; o >>= 1) {
        cp  += __shfl_down(cp, o);
        cg  += __shfl_down(cg, o);
        tp  += __shfl_down(tp, o);
        fnh += __shfl_down(fnh, o);
    }
    if ((tid & 63) == 0) {
        atomicAdd(&acc[0], cp);
        atomicAdd(&acc[1], cg);
        atomicAdd(&acc[2], tp);
        atomicAdd(&acc[3], fnh);
    }
    __syncthreads();
    if (tid < 4) atomicAdd(&cnt[b * 4 + tid], acc[tid]);
    __syncthreads();
    if (tid == 0) {
        __threadfence();                       // release this block's counts
        s_last = (atomicAdd(done, 1) == NB * STRIPS - 1);
    }
    __syncthreads();
    if (!s_last) return;                       // not the last block
    __threadfence();                           // acquire all counts

    if (tid < 3) {
        float sacc = 0.0f;
        for (int i = 0; i < NB; ++i) {
            float c0 = (float)atomicAdd(&cnt[i * 4 + 0], 0);
            float c1 = (float)atomicAdd(&cnt[i * 4 + 1], 0);
            float TP = (float)atomicAdd(&cnt[i * 4 + 2], 0);
            float c3 = (float)atomicAdd(&cnt[i * 4 + 3], 0);
            float FP = c0 - TP;
            float FN = c1 - c3;
            float v = (tid == 0) ? TP / (TP + FP + 1e-12f)
                    : (tid == 1) ? TP / (TP + FN + 1e-12f)
                                 : TP / (TP + FP + FN + 1e-12f);
            sacc += v;
        }
        out[tid] = sacc * (1.0f / NB);
    }
}

extern "C" void kernel_launch(void* const* d_in, const int* in_sizes, int n_in,
                              void* d_out, int out_size, void* d_ws, size_t ws_size,
                              hipStream_t stream) {
    (void)in_sizes; (void)n_in; (void)out_size; (void)ws_size;
    const float* y_pred = (const float*)d_in[0];
    const float* y_true = (const float*)d_in[1];
    float* out = (float*)d_out;

    u64* buf1 = (u64*)d_ws;                               // 1 MB
    u64* buf2 = buf1 + (size_t)NIMG * NWORDS;             // 1 MB
    int* cnt = (int*)(buf2 + (size_t)NIMG * NWORDS);      // 64 ints
    int* flags = cnt + 4 * NB;                            // 32 ints
    int* done = flags + NIMG;                             // 1 int

    hipLaunchKernelGGL(pack_kernel, dim3(2 * NB * HW / 16 / 256), dim3(256), 0, stream,
                       y_pred, y_true, buf1, cnt);
    hipLaunchKernelGGL(strip_kernel, dim3(NIMG * SSTRIPS), dim3(STHREADS), 0, stream,
                       buf1, buf2, flags, 0);             // phases 1..24
    hipLaunchKernelGGL(strip_kernel, dim3(NIMG * SSTRIPS), dim3(STHREADS), 0, stream,
                       buf2, buf1, flags, 1);             // phases 25..48, record
    hipLaunchKernelGGL(skel_kernel, dim3(NIMG), dim3(NTHREADS), 0, stream,
                       buf1, flags);                      // fallback, usually skipped
    hipLaunchKernelGGL(count_kernel, dim3(NB * STRIPS), dim3(256), 0, stream,
                       buf1, cnt, done, out);
}

// Round 7
// 112.629 us; speedup vs baseline: 1.0472x; 1.0472x over previous
//
#include <hip/hip_runtime.h>
#include <stdint.h>

#define HH 512
#define WW 512
#define HW (HH * WW)          // 262144 pixels per image
#define WPR 8                 // u64 words per row (global layout)
#define NWORDS (HH * WPR)     // 4096 words per image
#define NTHREADS 1024
#define NB 16                 // batch
#define NIMG (2 * NB)         // 32 masks

// padded LDS layout for final skel: rows -1..512, cols -1..8 (stride 10)
#define LSTR 10
#define LROWS (HH + 2)        // 514
#define LWORDS (LROWS * LSTR) // 5140 words

typedef unsigned long long u64;

// Zhang-Suen sub-step core on prebuilt neighbor views (bit k = pixel col k).
__device__ __forceinline__ u64 zs_core(u64 cc, u64 P2, u64 P3, u64 P4, u64 P5,
                                       u64 P6, u64 P7, u64 P8, u64 P9, int step) {
    u64 ab = P2 ^ P3;
    u64 s1 = ab ^ P4, c1 = (P2 & P3) | (ab & P4);
    u64 de = P5 ^ P6;
    u64 s2 = de ^ P7, c2 = (P5 & P6) | (de & P7);
    u64 s3 = P8 ^ P9, c3 = P8 & P9;
    u64 gh = s1 ^ s2;
    u64 b0 = gh ^ s3, c4 = (s1 & s2) | (gh & s3);
    u64 ij = c1 ^ c2;
    u64 s4 = ij ^ c3, c5 = (c1 & c2) | (ij & c3);
    u64 b1 = s4 ^ c4, c6 = s4 & c4;
    u64 b2 = c5 ^ c6, b3 = c5 & c6;

    u64 Bge2 = b1 | b2 | b3;
    u64 Ble6 = ~(b3 | (b2 & b1 & b0));

    u64 a1, a2, t;
    t = ~P2 & P3; a1 = t; a2 = 0ULL;
    t = ~P3 & P4; a2 |= a1 & t; a1 |= t;
    t = ~P4 & P5; a2 |= a1 & t; a1 |= t;
    t = ~P5 & P6; a2 |= a1 & t; a1 |= t;
    t = ~P6 & P7; a2 |= a1 & t; a1 |= t;
    t = ~P7 & P8; a2 |= a1 & t; a1 |= t;
    t = ~P8 & P9; a2 |= a1 & t; a1 |= t;
    t = ~P9 & P2; a2 |= a1 & t; a1 |= t;
    u64 Aeq1 = a1 & ~a2;

    u64 sccond = (step == 0) ? ~((P4 & P6) & (P2 | P8))
                             : ~((P2 & P8) & (P4 | P6));

    return cc & ~(Bge2 & Ble6 & Aeq1 & sccond);
}

// spread 16 bits to positions 0,4,8,...,60
__device__ __forceinline__ u64 spread4(u64 x) {
    x = (x | (x << 24)) & 0x000000FF000000FFULL;
    x = (x | (x << 12)) & 0x000F000F000F000FULL;
    x = (x | (x << 6))  & 0x0303030303030303ULL;
    x = (x | (x << 3))  & 0x1111111111111111ULL;
    return x;
}

// ---------------- pack: coalesced binarize (8192 blocks x 256 threads) -------
// One float4 per lane (16B/lane, fully coalesced). Wave covers 256 consecutive
// pixels; 4 ballots give the bit image; lanes 0-3 bit-spread them into the
// wave's 4 output u64 words. Block 0 zeroes cnt/flags/done.
__global__ __launch_bounds__(256)
void pack_kernel(const float* __restrict__ y_pred,
                 const float* __restrict__ y_true,
                 u64* __restrict__ bits /* buf1 */,
                 int* __restrict__ cnt /* 64 cnt + 32 flags + 1 done */) {
    int tid = threadIdx.x;
    if (blockIdx.x == 0 && tid < 4 * NB + NIMG + 1) cnt[tid] = 0;

    int t = blockIdx.x * 256 + tid;          // global thread 0..2097151
    int lane = tid & 63;
    size_t p0 = (size_t)t * 4;               // first pixel (concat space)
    const float* src;
    size_t off;
    if (p0 < (size_t)NB * HW) { src = y_pred; off = p0; }
    else                      { src = y_true; off = p0 - (size_t)NB * HW; }
    float4 a = *(const float4*)(src + off);
    unsigned nib = (unsigned)(a.x > 0.5f)
                 | ((unsigned)(a.y > 0.5f) << 1)
                 | ((unsigned)(a.z > 0.5f) << 2)
                 | ((unsigned)(a.w > 0.5f) << 3);
    u64 b0 = __ballot(nib & 1u);
    u64 b1 = __ballot(nib & 2u);
    u64 b2 = __ballot(nib & 4u);
    u64 b3 = __ballot(nib & 8u);
    if (lane < 4) {
        unsigned sh = lane * 16;
        u64 w = spread4((b0 >> sh) & 0xFFFFu)
              | (spread4((b1 >> sh) & 0xFFFFu) << 1)
              | (spread4((b2 >> sh) & 0xFFFFu) << 2)
              | (spread4((b3 >> sh) & 0xFFFFu) << 3);
        size_t wave = (size_t)t >> 6;
        bits[wave * 4 + lane] = w;
    }
}

// ---------------- strip thinning: 256 blocks, full GPU ----------------------
// Block owns 64 interior rows + 24-row halo each side; 12 local ZS iterations
// (24 phases) need no inter-block communication (validity shrinks 1 row/phase).
// Per-row dirty tracking (Cp protocol from the proven full-image kernel) skips
// stable words in the sparse tail. rec=1: record per-image "not converged".
#define SSTRIPS 8
#define SIROWS (HH / SSTRIPS)          // 64 interior rows
#define SHALO 24
#define SDROWS (SIROWS + 2 * SHALO)    // 112 domain rows
#define STHREADS (SDROWS * WPR)        // 896 threads, 1 word each
#define SITERS (SHALO / 2)             // 12 local iterations = 24 phases
#define SSTR 10
#define SLWORDS ((SDROWS + 2) * SSTR)  // 1140 words per buffer

__global__ __launch_bounds__(STHREADS)
void strip_kernel(const u64* __restrict__ src, u64* __restrict__ dst,
                  int* __restrict__ flags, int rec) {
    __shared__ u64 Mb[2][SLWORDS];     // 2 x 9120 B
    __shared__ unsigned int Cpb[2][SDROWS + 2];  // per-row change masks
    __shared__ int s_any[3];

    int bx = blockIdx.x;
    int img = bx >> 3;
    int s = bx & 7;
    int tid = threadIdx.x;             // 0..895
    int lane = tid & 63;
    int r = tid >> 3;                  // domain row 0..111
    int c = tid & 7;
    int gr = s * SIROWS - SHALO + r;   // global row of this thread's word

    for (int i = tid; i < SLWORDS; i += STHREADS) { Mb[0][i] = 0; Mb[1][i] = 0; }
    if (tid < SDROWS + 2) {
        Cpb[0][tid] = (tid >= 1 && tid <= SDROWS) ? 0x1FEu : 0u;
        Cpb[1][tid] = 0u;              // guards stay 0 forever
    }
    if (tid < 3) s_any[tid] = 0;
    __syncthreads();

    const u64* gsrc = src + (size_t)img * NWORDS;
    u64 v = (gr >= 0 && gr < HH) ? gsrc[gr * WPR + c] : 0ULL;
    int base = (r + 1) * SSTR + (c + 1);
    Mb[0][base] = v;

    unsigned dl = 0x1FEu;              // row-owner's "last sub-step" byte
    bool prevchg = true;
    int it = 0;
    bool done = false;
    for (;;) {
        for (int step = 0; step < 2; ++step) {
            __syncthreads();           // orders prior phase's writes
            if (step == 0 && it > 0) {
                if (s_any[(it + 2) % 3] == 0) { done = true; break; }
            }
            const u64* Ms = Mb[step];
            u64* Md = Mb[step ^ 1];
            const unsigned* CpS = Cpb[step];
            unsigned* CpD = Cpb[step ^ 1];

            unsigned need = ((CpS[r] | CpS[r + 1] | CpS[r + 2]) >> c) & 7u;
            bool chg = false;
            if (need) {
                u64 cc = Ms[base];
                u64 nv = cc;
                if (cc) {              // zero words can never gain pixels
                    u64 nm = Ms[base - SSTR - 1], nc = Ms[base - SSTR], np = Ms[base - SSTR + 1];
                    u64 cm = Ms[base - 1],                              cp = Ms[base + 1];
                    u64 sm = Ms[base + SSTR - 1], sc = Ms[base + SSTR], sp = Ms[base + SSTR + 1];
                    u64 P2 = nc;
                    u64 P3 = (nc >> 1) | (np << 63);
                    u64 P4 = (cc >> 1) | (cp << 63);
                    u64 P5 = (sc >> 1) | (sp << 63);
                    u64 P6 = sc;
                    u64 P7 = (sc << 1) | (sm >> 63);
                    u64 P8 = (cc << 1) | (cm >> 63);
                    u64 P9 = (nc << 1) | (nm >> 63);
                    nv = zs_core(cc, P2, P3, P4, P5, P6, P7, P8, P9, step);
                    chg = (nv != cc);
                }
                // Md holds state from 2 phases back; store only if changed
                // this phase or last (need==0 => prevchg==false: skip safe).
                if (chg | prevchg) Md[base] = nv;
            }
            prevchg = chg;
            u64 bal = __ballot(chg);   // wave = 8 rows x 8 cols
            if (bal && lane == 0) s_any[it % 3] = 1;   // benign same-value race
            if ((lane & 7) == 0) {     // one owner lane per row
                unsigned byte = ((unsigned)(bal >> lane) & 0xFFu) << 1;
                CpD[r + 1] = byte | dl;                // union of last two phases
                dl = byte;
            }
            if (step == 1 && tid == 0) s_any[(it + 1) % 3] = 0;
        }
        if (done) break;
        if (++it >= SITERS) break;
    }
    __syncthreads();                   // make last iteration's s_any visible
    int lastAny = done ? 0 : s_any[(SITERS - 1) % 3];

    // store interior rows (phase count even at both exits -> state in Mb[0])
    if (r >= SHALO && r < SHALO + SIROWS) {
        dst[(size_t)img * NWORDS + gr * WPR + c] = Mb[0][base];
    }
    if (rec && lastAny && tid == 0) flags[img] = 1;    // same-value races benign
}

// ---------------- final skeletonize: fallback, skips converged images --------
__global__ __launch_bounds__(NTHREADS, 4)
void skel_kernel(u64* __restrict__ bits, const int* __restrict__ flags) {
    __shared__ u64 Mb[2][LWORDS];
    __shared__ unsigned int Cpb[2][130];
    __shared__ int s_any[3];

    int bx = blockIdx.x;
    if (flags[bx] == 0) return;        // strips already converged this image

    int tid = threadIdx.x;
    int lane = tid & 63;
    int c = tid & 7;
    int rb = tid >> 3;

    u64* gm = bits + (size_t)bx * NWORDS;

    if (tid < LROWS) {
        int i = tid;
        if (i == 0 || i == LROWS - 1) {
            #pragma unroll
            for (int j = 0; j < LSTR; ++j) { Mb[0][i * LSTR + j] = 0; Mb[1][i * LSTR + j] = 0; }
        } else {
            Mb[0][i * LSTR + 0] = 0; Mb[0][i * LSTR + 9] = 0;
            Mb[1][i * LSTR + 0] = 0; Mb[1][i * LSTR + 9] = 0;
        }
    }
    {
        const ulonglong2* s2 = (const ulonglong2*)gm;
        #pragma unroll
        for (int k = 0; k < 2; ++k) {
            int i = k * NTHREADS + tid;
            ulonglong2 v = s2[i];
            int wi = i * 2;
            int r = wi >> 3, c2 = wi & 7;
            int li = (r + 1) * LSTR + c2 + 1;
            Mb[0][li] = v.x;
            Mb[0][li + 1] = v.y;
        }
    }
    if (tid < 130) {
        Cpb[0][tid] = (tid >= 1 && tid <= 128) ? 0x1FEu : 0u;
        Cpb[1][tid] = 0u;
    }
    if (tid < 3) s_any[tid] = 0;

    unsigned dl = 0x1FEu;
    bool prevchg = true;
    int base = (rb * 4 + 1) * LSTR + (c + 1);

    int it = 0;
    bool done = false;
    for (;;) {
        for (int step = 0; step < 2; ++step) {
            __syncthreads();
            if (step == 0 && it > 0) {
                if (s_any[(it + 2) % 3] == 0) { done = true; break; }
            }
            const u64* Ms = Mb[step];
            u64* Md = Mb[step ^ 1];
            const unsigned* CpS = Cpb[step];
            unsigned* CpD = Cpb[step ^ 1];

            unsigned need = ((CpS[rb] | CpS[rb + 1] | CpS[rb + 2]) >> c) & 7u;
            bool chg = false;
            if (need) {
                u64 Ca, Ea, Wa, Cb, Eb, Wb, Cc, Ec, Wc;
                {   int a = base - LSTR;
                    u64 x = Ms[a], mm = Ms[a - 1], pp = Ms[a + 1];
                    Ca = x; Ea = (x >> 1) | (pp << 63); Wa = (x << 1) | (mm >> 63); }
                {   int a = base;
                    u64 x = Ms[a], mm = Ms[a - 1], pp = Ms[a + 1];
                    Cb = x; Eb = (x >> 1) | (pp << 63); Wb = (x << 1) | (mm >> 63); }
                u64 nv0 = 0, nv1 = 0, nv2 = 0, nv3 = 0;
                {   int a = base + LSTR;
                    u64 x = Ms[a], mm = Ms[a - 1], pp = Ms[a + 1];
                    Cc = x; Ec = (x >> 1) | (pp << 63); Wc = (x << 1) | (mm >> 63);
                    if (Cb) nv0 = zs_core(Cb, Ca, Ea, Eb, Ec, Cc, Wc, Wb, Wa, step);
                    chg |= (nv0 != Cb);
                    Ca = Cb; Ea = Eb; Wa = Wb; Cb = Cc; Eb = Ec; Wb = Wc; }
                {   int a = base + 2 * LSTR;
                    u64 x = Ms[a], mm = Ms[a - 1], pp = Ms[a + 1];
                    Cc = x; Ec = (x >> 1) | (pp << 63); Wc = (x << 1) | (mm >> 63);
                    if (Cb) nv1 = zs_core(Cb, Ca, Ea, Eb, Ec, Cc, Wc, Wb, Wa, step);
                    chg |= (nv1 != Cb);
                    Ca = Cb; Ea = Eb; Wa = Wb; Cb = Cc; Eb = Ec; Wb = Wc; }
                {   int a = base + 3 * LSTR;
                    u64 x = Ms[a], mm = Ms[a - 1], pp = Ms[a + 1];
                    Cc = x; Ec = (x >> 1) | (pp << 63); Wc = (x << 1) | (mm >> 63);
                    if (Cb) nv2 = zs_core(Cb, Ca, Ea, Eb, Ec, Cc, Wc, Wb, Wa, step);
                    chg |= (nv2 != Cb);
                    Ca = Cb; Ea = Eb; Wa = Wb; Cb = Cc; Eb = Ec; Wb = Wc; }
                {   int a = base + 4 * LSTR;
                    u64 x = Ms[a], mm = Ms[a - 1], pp = Ms[a + 1];
                    Cc = x; Ec = (x >> 1) | (pp << 63); Wc = (x << 1) | (mm >> 63);
                    if (Cb) nv3 = zs_core(Cb, Ca, Ea, Eb, Ec, Cc, Wc, Wb, Wa, step);
                    chg |= (nv3 != Cb); }
                if (chg | prevchg) {
                    Md[base] = nv0;
                    Md[base + LSTR] = nv1;
                    Md[base + 2 * LSTR] = nv2;
                    Md[base + 3 * LSTR] = nv3;
                }
            }
            prevchg = chg;
            u64 bal = __ballot(chg);
            if (bal && lane == 0) s_any[it % 3] = 1;
            if ((lane & 7) == 0) {
                unsigned byte = ((unsigned)(bal >> lane) & 0xFFu) << 1;
                CpD[rb + 1] = byte | dl;
                dl = byte;
            }
            if (step == 1 && tid == 0) s_any[(it + 1) % 3] = 0;
        }
        if (done || it >= 1024) break;
        ++it;
    }

    {
        ulonglong2* d2 = (ulonglong2*)gm;
        #pragma unroll
        for (int k = 0; k < 2; ++k) {
            int i = k * NTHREADS + tid;
            int wi = i * 2;
            int r = wi >> 3, c2 = wi & 7;
            int li = (r + 1) * LSTR + c2 + 1;
            ulonglong2 v;
            v.x = Mb[0][li];
            v.y = Mb[0][li + 1];
            d2[i] = v;
        }
    }
}

// ---------------- count (+ fused final reduce): 8 strips/image, 128 blocks ---
#define STRIPS 8
#define SROWS (HH / STRIPS)
#define SR2 (SROWS + 6)

__device__ __forceinline__ u64 ldws(const u64* M, int r, int c) {
    return (c < 0 || c >= WPR) ? 0ULL : M[r * WPR + c];
}

__device__ __forceinline__ u64 dil3s(const u64* M, int r, int c) {
    u64 cm = ldws(M, r, c - 1), cc = ldws(M, r, c), cp = ldws(M, r, c + 1);
    u64 h = cc
          | (cc >> 1) | (cp << 63)
          | (cc >> 2) | (cp << 62)
          | (cc >> 3) | (cp << 61)
          | (cc << 1) | (cm >> 63)
          | (cc << 2) | (cm >> 62)
          | (cc << 3) | (cm >> 61);
    u64 um = ldws(M, r - 1, c - 1) | ldws(M, r + 1, c - 1) | ldws(M, r - 2, c - 1) | ldws(M, r + 2, c - 1);
    u64 uc = ldws(M, r - 1, c    ) | ldws(M, r + 1, c    ) | ldws(M, r - 2, c    ) | ldws(M, r + 2, c    );
    u64 up = ldws(M, r - 1, c + 1) | ldws(M, r + 1, c + 1) | ldws(M, r - 2, c + 1) | ldws(M, r + 2, c + 1);
    h |= uc
       | (uc >> 1) | (up << 63)
       | (uc >> 2) | (up << 62)
       | (uc << 1) | (um >> 63)
       | (uc << 2) | (um >> 62);
    h |= ldws(M, r - 3, c) | ldws(M, r + 3, c);
    return h;
}

__global__ __launch_bounds__(256)
void count_kernel(const u64* __restrict__ skel, int* __restrict__ cnt,
                  int* __restrict__ done, float* __restrict__ out) {
    __shared__ u64 P[SR2 * WPR];
    __shared__ u64 G[SR2 * WPR];
    __shared__ int acc[4];
    __shared__ int s_last;

    int b = blockIdx.x / STRIPS;
    int s = blockIdx.x % STRIPS;
    int tid = threadIdx.x;
    int r0 = s * SROWS - 3;

    const u64* sp = skel + (size_t)b * NWORDS;
    const u64* sg = skel + (size_t)(NB + b) * NWORDS;
    for (int i = tid; i < SR2 * WPR; i += 256) {
        int gr = r0 + (i >> 3);
        bool in = (gr >= 0 && gr < HH);
        int gi = gr * WPR + (i & 7);
        P[i] = in ? sp[gi] : 0ULL;
        G[i] = in ? sg[gi] : 0ULL;
    }
    if (tid < 4) acc[tid] = 0;
    __syncthreads();

    int cp = 0, cg = 0, tp = 0, fnh = 0;
    #pragma unroll
    for (int k = 0; k < 2; ++k) {
        int w = k * 256 + tid;
        int r = (w >> 3) + 3, c = w & 7;
        u64 pw = P[r * WPR + c], gw = G[r * WPR + c];
        cp  += __popcll(pw);
        cg  += __popcll(gw);
        tp  += __popcll(pw & dil3s(G, r, c));
        fnh += __popcll(gw & dil3s(P, r, c));
    }
    #pragma unroll
    for (int o = 32; o > 0; o >>= 1) {
        cp  += __shfl_down(cp, o);
        cg  += __shfl_down(cg, o);
        tp  += __shfl_down(tp, o);
        fnh += __shfl_down(fnh, o);
    }
    if ((tid & 63) == 0) {
        atomicAdd(&acc[0], cp);
        atomicAdd(&acc[1], cg);
        atomicAdd(&acc[2], tp);
        atomicAdd(&acc[3], fnh);
    }
    __syncthreads();
    if (tid < 4) atomicAdd(&cnt[b * 4 + tid], acc[tid]);
    __syncthreads();
    if (tid == 0) {
        __threadfence();                       // release this block's counts
        s_last = (atomicAdd(done, 1) == NB * STRIPS - 1);
    }
    __syncthreads();
    if (!s_last) return;                       // not the last block
    __threadfence();                           // acquire all counts

    if (tid < 3) {
        float sacc = 0.0f;
        for (int i = 0; i < NB; ++i) {
            float c0 = (float)atomicAdd(&cnt[i * 4 + 0], 0);
            float c1 = (float)atomicAdd(&cnt[i * 4 + 1], 0);
            float TP = (float)atomicAdd(&cnt[i * 4 + 2], 0);
            float c3 = (float)atomicAdd(&cnt[i * 4 + 3], 0);
            float FP = c0 - TP;
            float FN = c1 - c3;
            float v = (tid == 0) ? TP / (TP + FP + 1e-12f)
                    : (tid == 1) ? TP / (TP + FN + 1e-12f)
                                 : TP / (TP + FP + FN + 1e-12f);
            sacc += v;
        }
        out[tid] = sacc * (1.0f / NB);
    }
}

extern "C" void kernel_launch(void* const* d_in, const int* in_sizes, int n_in,
                              void* d_out, int out_size, void* d_ws, size_t ws_size,
                              hipStream_t stream) {
    (void)in_sizes; (void)n_in; (void)out_size; (void)ws_size;
    const float* y_pred = (const float*)d_in[0];
    const float* y_true = (const float*)d_in[1];
    float* out = (float*)d_out;

    u64* buf1 = (u64*)d_ws;                               // 1 MB
    u64* buf2 = buf1 + (size_t)NIMG * NWORDS;             // 1 MB
    int* cnt = (int*)(buf2 + (size_t)NIMG * NWORDS);      // 64 ints
    int* flags = cnt + 4 * NB;                            // 32 ints
    int* done = flags + NIMG;                             // 1 int

    hipLaunchKernelGGL(pack_kernel, dim3(2 * NB * HW / 4 / 256), dim3(256), 0, stream,
                       y_pred, y_true, buf1, cnt);
    hipLaunchKernelGGL(strip_kernel, dim3(NIMG * SSTRIPS), dim3(STHREADS), 0, stream,
                       buf1, buf2, flags, 0);             // phases 1..24
    hipLaunchKernelGGL(strip_kernel, dim3(NIMG * SSTRIPS), dim3(STHREADS), 0, stream,
                       buf2, buf1, flags, 1);             // phases 25..48, record
    hipLaunchKernelGGL(skel_kernel, dim3(NIMG), dim3(NTHREADS), 0, stream,
                       buf1, flags);                      // fallback, usually skipped
    hipLaunchKernelGGL(count_kernel, dim3(NB * STRIPS), dim3(256), 0, stream,
                       buf1, cnt, done, out);
}